// Round 1
// baseline (380.071 us; speedup 1.0000x reference)
//
#include <hip/hip_runtime.h>

// Problem shape: preds (N=8, S=6, C=4, H=512, W=512) fp32, targets (8,6,512,512) int32.
// out = (1/N) * sum over all (n,s,h,w) of [logsumexp_c(preds) - preds[target]]
//
// Memory-bound: ~240 MiB read / launch. Strategy: 1 thread = 4 consecutive
// pixels (float4 per channel plane, int4 targets), wave64 shuffle reduce,
// LDS cross-wave reduce, one atomicAdd per block.

#define HW      (512 * 512)
#define QUADS   (HW / 4)        // 65536 float4 groups per channel plane
#define NS      48              // N*S
#define NBLOCKS ((NS * QUADS) / 256)  // 12288, exact
#define INV_N   0.125f

__device__ __forceinline__ float nll_one(float a, float b, float c, float d, int t) {
    float m = fmaxf(fmaxf(a, b), fmaxf(c, d));
    float s = __expf(a - m) + __expf(b - m) + __expf(c - m) + __expf(d - m);
    float lse = m + __logf(s);
    float xt = (t == 0) ? a : ((t == 1) ? b : ((t == 2) ? c : d));
    return lse - xt;
}

__global__ __launch_bounds__(256) void ce_loss_kernel(const float* __restrict__ preds,
                                                      const int* __restrict__ targets,
                                                      float* __restrict__ out) {
    const int g = blockIdx.x * 256 + threadIdx.x;   // global quad index [0, NS*QUADS)
    const int ns = g >> 16;                          // g / QUADS
    const int q  = g & (QUADS - 1);                  // g % QUADS

    const float4* __restrict__ p4 = (const float4*)preds;
    const int4*   __restrict__ t4 = (const int4*)targets;

    // channel plane c for slab ns starts at quad (ns*4 + c) * QUADS
    const int base = (ns << 2) * QUADS + q;
    float4 x0 = p4[base];
    float4 x1 = p4[base + QUADS];
    float4 x2 = p4[base + 2 * QUADS];
    float4 x3 = p4[base + 3 * QUADS];
    int4   t  = t4[ns * QUADS + q];

    float lsum = nll_one(x0.x, x1.x, x2.x, x3.x, t.x)
               + nll_one(x0.y, x1.y, x2.y, x3.y, t.y)
               + nll_one(x0.z, x1.z, x2.z, x3.z, t.z)
               + nll_one(x0.w, x1.w, x2.w, x3.w, t.w);

    // wave-64 reduction
    #pragma unroll
    for (int off = 32; off > 0; off >>= 1)
        lsum += __shfl_down(lsum, off, 64);

    __shared__ float wsum[4];
    const int lane = threadIdx.x & 63;
    const int wave = threadIdx.x >> 6;
    if (lane == 0) wsum[wave] = lsum;
    __syncthreads();
    if (threadIdx.x == 0) {
        float s = wsum[0] + wsum[1] + wsum[2] + wsum[3];
        atomicAdd(out, s * INV_N);
    }
}

extern "C" void kernel_launch(void* const* d_in, const int* in_sizes, int n_in,
                              void* d_out, int out_size, void* d_ws, size_t ws_size,
                              hipStream_t stream) {
    const float* preds   = (const float*)d_in[0];
    const int*   targets = (const int*)d_in[1];
    float*       out     = (float*)d_out;

    // d_out is poisoned to 0xAA before every timed launch; zero it (graph-capturable).
    hipMemsetAsync(d_out, 0, sizeof(float), stream);
    ce_loss_kernel<<<NBLOCKS, 256, 0, stream>>>(preds, targets, out);
}

// Round 2
// 310.769 us; speedup vs baseline: 1.2230x; 1.2230x over previous
//
#include <hip/hip_runtime.h>

// Problem: preds (N=8,S=6,C=4,H=512,W=512) fp32, targets (8,6,512,512) int.
// out = (1/N) * sum [logsumexp_c(preds) - preds[target]]   (scalar)
//
// R1 post-mortem: 12288 same-address atomicAdds serialized the kernel
// (168 us fixed, independent of HBM traffic). R2: two-stage reduction,
// zero contended atomics.

#define HW        (512 * 512)
#define QUADS     (HW / 4)          // 65536 float4 groups per channel plane
#define NS        48                // N*S
#define TOTALQ    (NS * QUADS)      // 3145728 quads
#define NBLK      1024
#define ITERS     (TOTALQ / (NBLK * 256))   // 12, exact
#define INV_N     0.125f

__device__ __forceinline__ float nll_one(float a, float b, float c, float d, int t) {
    float m = fmaxf(fmaxf(a, b), fmaxf(c, d));
    float s = __expf(a - m) + __expf(b - m) + __expf(c - m) + __expf(d - m);
    float lse = m + __logf(s);
    float xt = (t == 0) ? a : ((t == 1) ? b : ((t == 2) ? c : d));
    return lse - xt;
}

__global__ __launch_bounds__(256) void ce_partial(const float* __restrict__ preds,
                                                  const int* __restrict__ targets,
                                                  float* __restrict__ part) {
    const float4* __restrict__ p4 = (const float4*)preds;
    const int4*   __restrict__ t4 = (const int4*)targets;

    float lsum = 0.0f;
    // each block owns a contiguous chunk of ITERS*256 quads
    const int g0 = blockIdx.x * (ITERS * 256) + threadIdx.x;
    #pragma unroll
    for (int it = 0; it < ITERS; ++it) {
        const int g  = g0 + it * 256;
        const int ns = g >> 16;            // g / QUADS
        const int q  = g & (QUADS - 1);    // g % QUADS
        const int base = (ns << 2) * QUADS + q;
        float4 x0 = p4[base];
        float4 x1 = p4[base + QUADS];
        float4 x2 = p4[base + 2 * QUADS];
        float4 x3 = p4[base + 3 * QUADS];
        int4   t  = t4[ns * QUADS + q];
        lsum += nll_one(x0.x, x1.x, x2.x, x3.x, t.x)
              + nll_one(x0.y, x1.y, x2.y, x3.y, t.y)
              + nll_one(x0.z, x1.z, x2.z, x3.z, t.z)
              + nll_one(x0.w, x1.w, x2.w, x3.w, t.w);
    }

    // wave-64 reduction
    #pragma unroll
    for (int off = 32; off > 0; off >>= 1)
        lsum += __shfl_down(lsum, off, 64);

    __shared__ float wsum[4];
    const int lane = threadIdx.x & 63;
    const int wave = threadIdx.x >> 6;
    if (lane == 0) wsum[wave] = lsum;
    __syncthreads();
    if (threadIdx.x == 0)
        part[blockIdx.x] = wsum[0] + wsum[1] + wsum[2] + wsum[3];
}

__global__ __launch_bounds__(256) void ce_final(const float* __restrict__ part,
                                                float* __restrict__ out) {
    float lsum = 0.0f;
    #pragma unroll
    for (int i = 0; i < NBLK / 256; ++i)
        lsum += part[i * 256 + threadIdx.x];

    #pragma unroll
    for (int off = 32; off > 0; off >>= 1)
        lsum += __shfl_down(lsum, off, 64);

    __shared__ float wsum[4];
    const int lane = threadIdx.x & 63;
    const int wave = threadIdx.x >> 6;
    if (lane == 0) wsum[wave] = lsum;
    __syncthreads();
    if (threadIdx.x == 0)
        out[0] = (wsum[0] + wsum[1] + wsum[2] + wsum[3]) * INV_N;
}

extern "C" void kernel_launch(void* const* d_in, const int* in_sizes, int n_in,
                              void* d_out, int out_size, void* d_ws, size_t ws_size,
                              hipStream_t stream) {
    const float* preds   = (const float*)d_in[0];
    const int*   targets = (const int*)d_in[1];
    float*       part    = (float*)d_ws;     // NBLK floats = 4 KiB scratch
    float*       out     = (float*)d_out;

    ce_partial<<<NBLK, 256, 0, stream>>>(preds, targets, part);
    ce_final<<<1, 256, 0, stream>>>(part, out);
}